// Round 9
// baseline (374.653 us; speedup 1.0000x reference)
//
#include <hip/hip_runtime.h>
#include <hip/hip_bf16.h>
#include <stdint.h>

typedef __hip_bfloat16 bf16;
typedef __attribute__((ext_vector_type(8))) short bv8;    // 8 x bf16 (mfma A/B frag)
typedef __attribute__((ext_vector_type(4))) float f32x4;  // mfma C/D frag

// Problem constants: B=2, T=1024, S_ENC=1024, D=2048, NQ=16, NKV=8, H=256, SKV=2048

__device__ __forceinline__ f32x4 mfma16(bv8 a, bv8 b, f32x4 c) {
  return __builtin_amdgcn_mfma_f32_16x16x32_bf16(a, b, c, 0, 0, 0);
}

__device__ __forceinline__ void gload16(const void* g, void* lds) {
  __builtin_amdgcn_global_load_lds((const __attribute__((address_space(1))) void*)g,
                                   (__attribute__((address_space(3))) void*)lds, 16, 0, 0);
}

__device__ __forceinline__ void storeC(float* p, float v) { *p = v; }
__device__ __forceinline__ void storeC(bf16* p, float v) { *p = __float2bfloat16(v); }

// ---------------- merged elementwise f32 -> bf16 (both activations, 1 launch) ----------------
__global__ void cast2_f32_bf16(const float* __restrict__ a, const float* __restrict__ b,
                               bf16* __restrict__ da, bf16* __restrict__ db, int n4each) {
  int i = blockIdx.x * blockDim.x + threadIdx.x;
  const float* s;
  bf16* d;
  if (i < n4each) { s = a; d = da; }
  else            { s = b; d = db; i -= n4each; }
  float4 v = reinterpret_cast<const float4*>(s)[i];
  bf16 t[4] = {__float2bfloat16(v.x), __float2bfloat16(v.y),
               __float2bfloat16(v.z), __float2bfloat16(v.w)};
  reinterpret_cast<uint64_t*>(d)[i] = *reinterpret_cast<uint64_t*>(t);
}

// ------- merged QKV weight transpose+cast: 32 head-slices [2048][256] -> [256][2048] -------
__global__ void transpose_cast_qkv(const float* __restrict__ q_w, const float* __restrict__ k_w,
                                   const float* __restrict__ v_w, bf16* __restrict__ dst) {
  __shared__ float tile[32][33];
  const int z = blockIdx.z;
  const float* s = (z < 16) ? q_w + (size_t)z * 524288
                 : (z < 24) ? k_w + (size_t)(z - 16) * 524288
                            : v_w + (size_t)(z - 24) * 524288;
  bf16* d = dst + (size_t)z * 524288;
  const int R = 2048, C = 256;
  const int c0 = blockIdx.x * 32, r0 = blockIdx.y * 32;
  const int x = threadIdx.x, y = threadIdx.y;
#pragma unroll
  for (int i = 0; i < 32; i += 8)
    tile[y + i][x] = s[(size_t)(r0 + y + i) * C + c0 + x];
  __syncthreads();
#pragma unroll
  for (int i = 0; i < 32; i += 8)
    d[(size_t)(c0 + y + i) * R + r0 + x] = __float2bfloat16(tile[x][y + i]);
}

// ------- O-weight transpose+cast: [4096][2048] -> [2048][4096] -------
__global__ void transpose_cast(const float* __restrict__ src, bf16* __restrict__ dst,
                               int R, int C) {
  __shared__ float tile[32][33];
  const float* s = src;
  bf16* d = dst;
  const int c0 = blockIdx.x * 32, r0 = blockIdx.y * 32;
  const int x = threadIdx.x, y = threadIdx.y;
#pragma unroll
  for (int i = 0; i < 32; i += 8)
    tile[y + i][x] = s[(size_t)(r0 + y + i) * C + c0 + x];
  __syncthreads();
#pragma unroll
  for (int i = 0; i < 32; i += 8)
    d[(size_t)(c0 + y + i) * R + r0 + x] = __float2bfloat16(tile[x][y + i]);
}

// ------- merged V transpose: z<16 self (ld 8192, t0=0), else cross (ld 4096, t0=1024) -------
__global__ void transpose_v2(const bf16* __restrict__ vself, const bf16* __restrict__ vcross,
                             bf16* __restrict__ dst) {
  __shared__ bf16 tile[32][33];
  const int z = blockIdx.z;
  const int zz = z & 15, b = zz >> 3, kvh = zz & 7;
  const bool cross = z >= 16;
  const bf16* srcb = cross ? vcross : vself;
  const int src_ld = cross ? 4096 : 8192;
  const int t0 = cross ? 1024 : 0;
  const bf16* s = srcb + (size_t)(b * 1024) * src_ld + kvh * 256;
  bf16* d = dst + (size_t)(zz * 256) * 2048 + t0;
  const int h0 = blockIdx.x * 32, tt0 = blockIdx.y * 32;
  const int x = threadIdx.x, y = threadIdx.y;
#pragma unroll
  for (int i = 0; i < 32; i += 8)
    tile[y + i][x] = s[(size_t)(tt0 + y + i) * src_ld + h0 + x];
  __syncthreads();
#pragma unroll
  for (int i = 0; i < 32; i += 8)
    d[(size_t)(h0 + y + i) * 2048 + tt0 + x] = tile[x][y + i];
}

// ---------------- GEMM body: C[M][N] = A[M][K] * Bt[N][K]^T (m97 128x128, BK=32) ----------------
template <typename CT>
__device__ __forceinline__ void gemm_body(const bf16* __restrict__ A, const bf16* __restrict__ Bt,
                                          CT* __restrict__ C, int N, int K,
                                          int m0, int n0, int kbase, int ksteps) {
  __shared__ __align__(16) bf16 As[128 * 32];
  __shared__ __align__(16) bf16 Bs[128 * 32];
  const int tid = threadIdx.x;
  const int w = tid >> 6, l = tid & 63;
  const int wr = w >> 1, wc = w & 1;
  const int l15 = l & 15, lhi = l >> 4;
  const bf16* ag = A + (size_t)(m0 + (tid >> 2)) * K + kbase + (tid & 3) * 8;
  const bf16* bg = Bt + (size_t)(n0 + (tid >> 2)) * K + kbase + (tid & 3) * 8;
  bf16* asw = As + w * 512;
  bf16* bsw = Bs + w * 512;
  f32x4 acc[4][4] = {};
  for (int k0 = 0; k0 < ksteps; k0 += 32) {
    gload16(ag + k0, asw);
    gload16(ag + (size_t)64 * K + k0, asw + 2048);
    gload16(bg + k0, bsw);
    gload16(bg + (size_t)64 * K + k0, bsw + 2048);
    asm volatile("s_waitcnt vmcnt(0)" ::: "memory");
    __syncthreads();
    bv8 af[4], bfv[4];
#pragma unroll
    for (int m = 0; m < 4; ++m)
      af[m] = *reinterpret_cast<const bv8*>(As + (wr * 64 + m * 16 + l15) * 32 + lhi * 8);
#pragma unroll
    for (int n = 0; n < 4; ++n)
      bfv[n] = *reinterpret_cast<const bv8*>(Bs + (wc * 64 + n * 16 + l15) * 32 + lhi * 8);
#pragma unroll
    for (int m = 0; m < 4; ++m)
#pragma unroll
      for (int n = 0; n < 4; ++n)
        acc[m][n] = mfma16(af[m], bfv[n], acc[m][n]);
    __syncthreads();
  }
  const int r0 = m0 + wr * 64 + lhi * 4;
  const int c0 = n0 + wc * 64 + l15;
#pragma unroll
  for (int m = 0; m < 4; ++m)
#pragma unroll
    for (int n = 0; n < 4; ++n) {
      f32x4 v = acc[m][n];
#pragma unroll
      for (int j = 0; j < 4; ++j)
        storeC(&C[(size_t)(r0 + m * 16 + j) * N + c0 + n * 16], v[j]);
    }
}

// merged self+cross projection GEMM: bx<64 -> self (N=8192), else cross (N=4096)
__launch_bounds__(256)
__global__ void gemm_proj(const bf16* __restrict__ hid, const bf16* __restrict__ enc,
                          const bf16* __restrict__ wqkvt, bf16* __restrict__ cself,
                          bf16* __restrict__ ccross) {
  const int bx = blockIdx.x;
  const bool cross = bx >= 64;
  const bf16* A = cross ? enc : hid;
  const bf16* Bt = cross ? wqkvt + 8388608 : wqkvt;
  bf16* C = cross ? ccross : cself;
  const int N = cross ? 4096 : 8192;
  const int n0 = (cross ? bx - 64 : bx) * 128;
  gemm_body<bf16>(A, Bt, C, N, 2048, blockIdx.y * 128, n0, 0, 2048);
}

// O-projection with split-K=2: z=0 -> out, z=1 -> partial p1 (both f32 [2048][2048])
__launch_bounds__(256)
__global__ void gemm_osplit(const bf16* __restrict__ A, const bf16* __restrict__ Bt,
                            float* __restrict__ out, float* __restrict__ p1) {
  float* C = blockIdx.z ? p1 : out;
  gemm_body<float>(A, Bt, C, 2048, 4096, blockIdx.y * 128, blockIdx.x * 128,
                   blockIdx.z * 2048, 2048);
}

// combine: out += p1 (float4)
__global__ void add_inplace(float* __restrict__ out, const float* __restrict__ p1, int n4) {
  int i = blockIdx.x * blockDim.x + threadIdx.x;
  if (i >= n4) return;
  float4 a = reinterpret_cast<float4*>(out)[i];
  float4 b = reinterpret_cast<const float4*>(p1)[i];
  a.x += b.x; a.y += b.y; a.z += b.z; a.w += b.w;
  reinterpret_cast<float4*>(out)[i] = a;
}

// ---------------- RMSNorm (+optional RoPE) + scale ----------------
template <bool ROPE>
__launch_bounds__(256)
__global__ void norm_finalize(const bf16* __restrict__ src, int src_ld, int src_col0,
                              const float* __restrict__ scale,
                              const int* __restrict__ pos_ids,
                              bf16* __restrict__ dst, int nheads, int dst_S, int dst_t0,
                              float mul) {
  const int gid = blockIdx.x * 4 + (threadIdx.x >> 6);
  const int l = threadIdx.x & 63;
  const int token = gid / nheads;
  const int n = gid - token * nheads;
  const int b = token >> 10;
  const int t = token & 1023;
  const size_t soff = (size_t)token * src_ld + src_col0 + n * 256 + l * 4;
  bf16 xb[4];
  *reinterpret_cast<uint64_t*>(xb) = *reinterpret_cast<const uint64_t*>(src + soff);
  float x[4];
#pragma unroll
  for (int c = 0; c < 4; ++c) x[c] = __bfloat162float(xb[c]);
  float ss = x[0] * x[0] + x[1] * x[1] + x[2] * x[2] + x[3] * x[3];
#pragma unroll
  for (int d = 1; d < 64; d <<= 1) ss += __shfl_xor(ss, d);
  const float r = rsqrtf(ss * (1.0f / 256.0f) + 1e-6f);
  float v[4];
#pragma unroll
  for (int c = 0; c < 4; ++c) v[c] = x[c] * r * (1.0f + scale[l * 4 + c]);
  if (ROPE) {
    const float pos = (float)pos_ids[token];
    float o[4];
#pragma unroll
    for (int c = 0; c < 4; ++c) {
      const int j = (l & 31) * 4 + c;
      const float inv_ts = exp2f(-(float)j * 0.10381025296523007f);
      const float arg = pos * inv_ts;
      const float sj = sinf(arg), cj = cosf(arg);
      const float partner = __shfl_xor(v[c], 32);
      o[c] = (l < 32) ? (v[c] * cj - partner * sj) : (v[c] * cj + partner * sj);
    }
#pragma unroll
    for (int c = 0; c < 4; ++c) v[c] = o[c];
  }
  bf16 ob[4];
#pragma unroll
  for (int c = 0; c < 4; ++c) ob[c] = __float2bfloat16(v[c] * mul);
  const size_t doff = ((size_t)((b * nheads + n) * dst_S + dst_t0 + t)) * 256 + l * 4;
  *reinterpret_cast<uint64_t*>(dst + doff) = *reinterpret_cast<uint64_t*>(ob);
}

// ---------------- fused attention (QBLK=32, KVBLK=32: 2 blocks/CU, 4 waves/SIMD) ----------------
// grid 512 blocks (XCD-swizzled: 32 qt x 16 b*kvh), 512 thr / 8 waves, ~70KB LDS.
// QK role: wave (g=w>>2, qs=(w>>1)&1, sh=w&1): 1 q-subtile x 1 s-subtile -> 8 K-reads, 8 MFMA.
// PV role: wave (g, hq=w&3): 2 q-subtiles x 4 ht -> 2 P + 4 V reads, 8 MFMA.
// K tile [32 s][256 h] swizzle ^((row&7)<<4) (512B rows); V^T tile [256 h][32 s]
// swizzle ^((h&3)<<4) (64B rows); pre-swizzled global srcs + linear gload_lds dests.
// Softcap bounds logits to +-50 -> plain sum-softmax; exp2-based softcap.
__launch_bounds__(512, 4)
__global__ void attn_kernel(const bf16* __restrict__ qb, const bf16* __restrict__ kb,
                            const bf16* __restrict__ vt, bf16* __restrict__ attn_out) {
  __shared__ __align__(16) bf16 Ks[2][32 * 256];   // 16KB each
  __shared__ __align__(16) bf16 Vs[2][256 * 32];   // 16KB each
  __shared__ __align__(16) bf16 pbuf[2][32 * 36];  // [g][32 q][36 pad]
  __shared__ float rsb[2][2][2][4][4];             // [g][qs][sh][j][lhi]
  const int lin = blockIdx.x + 32 * blockIdx.y;
  const int kvc = (lin & 7) | (((lin >> 8) & 1) << 3);  // XCD-coherent, bijective
  const int qt  = (lin >> 3) & 31;
  const int b = kvc >> 3, kvh = kvc & 7;
  const int tid = threadIdx.x, w = tid >> 6, l = tid & 63;
  const int g = w >> 2, qs = (w >> 1) & 1, sh = w & 1, hq = w & 3;
  const int n = kvh * 2 + g;
  const int l15 = l & 15, lhi = l >> 4;
  const int xr = (l15 & 7) << 4;  // K frag-read byte swizzle

  const bf16* kbase = kb + (size_t)(b * 8 + kvh) * 2048 * 256;
  const bf16* vbase = vt + (size_t)(b * 8 + kvh) * 256 * 2048;

  // staging sources (pre-swizzled cols, tile-invariant part); 2 chunks per operand
  const int kcol = (((tid & 31) * 16) ^ (((tid >> 5) & 7) << 4)) >> 1;
  const bf16* ksrc0 = kbase + (size_t)(tid >> 5) * 256 + kcol;          // rows 0..15
  const bf16* ksrc1 = kbase + (size_t)(16 + (tid >> 5)) * 256 + kcol;   // rows 16..31
  const int vcol = (((tid & 3) * 16) ^ (((tid >> 2) & 3) << 4)) >> 1;
  const bf16* vsrc0 = vbase + (size_t)(tid >> 2) * 2048 + vcol;         // h 0..127
  const bf16* vsrc1 = vbase + (size_t)(128 + (tid >> 2)) * 2048 + vcol; // h 128..255

#define STAGE_KV(bb, s0)                                         \
  do {                                                           \
    gload16(ksrc0 + (size_t)(s0) * 256, &Ks[bb][w * 512]);       \
    gload16(ksrc1 + (size_t)(s0) * 256, &Ks[bb][4096 + w * 512]);\
    gload16(vsrc0 + (s0), &Vs[bb][w * 512]);                     \
    gload16(vsrc1 + (s0), &Vs[bb][4096 + w * 512]);              \
  } while (0)

  // Q fragments: this wave's QK q-subtile (head n), register-resident
  const bf16* qp = qb + ((size_t)(b * 16 + n) * 1024 + qt * 32 + qs * 16 + l15) * 256 + lhi * 8;
  bv8 qf[8];
#pragma unroll
  for (int f = 0; f < 8; ++f) qf[f] = *reinterpret_cast<const bv8*>(qp + f * 32);

  f32x4 oacc[2][4] = {};  // [q][i]: O rows q*16+lhi*4+j, cols (hq*4+i)*16+l15
  float rs[4] = {};

  const int nt = qt + 33;  // qt+1 self tiles + 32 cross tiles (32-wide)

  STAGE_KV(0, 0);
  asm volatile("s_waitcnt vmcnt(0)" ::: "memory");
  __syncthreads();

  for (int it = 0; it < nt; ++it) {
    const int cur = it & 1;
    if (it + 1 < nt) {  // prefetch next tile into other buffer
      const int itn = it + 1;
      const int s1 = (itn <= qt) ? itn * 32 : 1024 + (itn - qt - 1) * 32;
      STAGE_KV(cur ^ 1, s1);
    }
    // ---- QK^T: wave's (qs, sh) 16x16 logit tile, K from LDS ----
    f32x4 lacc = {};
    const int krow = (sh * 16 + l15) * 256;
    __builtin_amdgcn_s_setprio(1);
#pragma unroll
    for (int f = 0; f < 8; ++f) {
      const int off = krow + (((f * 64 + lhi * 16) ^ xr) >> 1);
      bv8 kf = *reinterpret_cast<const bv8*>(&Ks[cur][off]);
      lacc = mfma16(qf[f], kf, lacc);
    }
    __builtin_amdgcn_s_setprio(0);
    // ---- softcap + mask + exp (exp2-based) -> P tile ----
    const bool diag = (it == qt);
#pragma unroll
    for (int j = 0; j < 4; ++j) {
      const float raw = lacc[j];
      // p = exp(50*tanh(raw/50)) = exp2(72.1348 - 144.2695/(e2+1)), e2 = exp2(raw*.04*log2e)
      const float e2 = exp2f(raw * 0.057707801635559464f);
      const int trow = qs * 16 + lhi * 4 + j;
      const bool ok = !diag || (sh * 16 + l15 <= trow);
      const float p =
          ok ? exp2f(72.13475204444817f - __fdividef(144.26950408889634f, e2 + 1.f)) : 0.f;
      rs[j] += p;
      pbuf[g][trow * 36 + sh * 16 + l15] = __float2bfloat16(p);
    }
    __syncthreads();  // P visible to g-group PV readers
    // ---- PV: wave's 4 ht x 2 q-subtiles, V from LDS ----
    __builtin_amdgcn_s_setprio(1);
    bv8 pa[2];
#pragma unroll
    for (int q = 0; q < 2; ++q)
      pa[q] = *reinterpret_cast<const bv8*>(&pbuf[g][(q * 16 + l15) * 36 + lhi * 8]);
#pragma unroll
    for (int i = 0; i < 4; ++i) {
      const int off = ((hq * 4 + i) * 16 + l15) * 32 + ((lhi * 8) ^ ((l15 & 3) << 3));
      bv8 vf = *reinterpret_cast<const bv8*>(&Vs[cur][off]);
      oacc[0][i] = mfma16(pa[0], vf, oacc[0][i]);
      oacc[1][i] = mfma16(pa[1], vf, oacc[1][i]);
    }
    __builtin_amdgcn_s_setprio(0);
    asm volatile("s_waitcnt vmcnt(0)" ::: "memory");  // staged tile landed
    __syncthreads();  // K/V/pbuf reads done; next iter may overwrite
  }
#undef STAGE_KV
  // ---- rowsum combine across sh halves, then normalize + store ----
#pragma unroll
  for (int j = 0; j < 4; ++j) {
    float s = rs[j];
    s += __shfl_xor(s, 1);
    s += __shfl_xor(s, 2);
    s += __shfl_xor(s, 4);
    s += __shfl_xor(s, 8);
    if (l15 == 0) rsb[g][qs][sh][j][lhi] = s;
  }
  __syncthreads();
  float invr[2][4];
#pragma unroll
  for (int q = 0; q < 2; ++q)
#pragma unroll
    for (int j = 0; j < 4; ++j)
      invr[q][j] = 1.0f / (rsb[g][q][0][j][lhi] + rsb[g][q][1][j][lhi]);
  bf16* op = attn_out + ((size_t)(b * 1024 + qt * 32 + lhi * 4) * 4096) + n * 256 + l15;
#pragma unroll
  for (int q = 0; q < 2; ++q)
#pragma unroll
    for (int i = 0; i < 4; ++i)
#pragma unroll
      for (int j = 0; j < 4; ++j)
        op[(size_t)(q * 16 + j) * 4096 + (hq * 4 + i) * 16] =
            __float2bfloat16(oacc[q][i][j] * invr[q][j]);
}

// ---------------- host launcher ----------------
extern "C" void kernel_launch(void* const* d_in, const int* in_sizes, int n_in,
                              void* d_out, int out_size, void* d_ws, size_t ws_size,
                              hipStream_t stream) {
  (void)in_sizes; (void)n_in; (void)out_size; (void)ws_size;
  const float* hidden = (const float*)d_in[0];
  const float* enc    = (const float*)d_in[1];
  const int*   pos    = (const int*)d_in[2];
  // d_in[3] = merged_attention_mask: deterministic (causal|ones) -> computed analytically
  const float* q_w = (const float*)d_in[4];
  const float* k_w = (const float*)d_in[5];
  const float* v_w = (const float*)d_in[6];
  const float* o_w = (const float*)d_in[7];
  const float* q_s = (const float*)d_in[8];
  const float* k_s = (const float*)d_in[9];
  float* out = (float*)d_out;

  // workspace layout (117,440,512 bytes), write-before-read aliasing (single stream):
  char* base = (char*)d_ws;
  bf16* hid_b  = (bf16*)(base + 0);          // [2048][2048]
  bf16* enc_b  = (bf16*)(base + 8388608);    // [2048][2048]
  bf16* qb     = (bf16*)(base + 0);          // [2][16][1024][256]
  bf16* wqkvt  = (bf16*)(base + 16777216);   // [8192][2048] = qwt|kwt|vwt
  bf16* kbuf   = (bf16*)(base + 16777216);   // [2][8][2048][256]
  bf16* vtb    = (bf16*)(base + 33554432);   // [2][8][256][2048]
  bf16* owt    = (bf16*)(base + 50331648);   // [2048][4096]
  bf16* cself  = (bf16*)(base + 67108864);   // [2048][8192] = q|k_self|v_self
  bf16* attn_b = (bf16*)(base + 67108864);   // [2048][4096]
  float* p1    = (float*)(base + 83886080);  // [2048][2048] f32 split-K partial
  bf16* ccross = (bf16*)(base + 100663296);  // [2048][4096] = k_cross|v_cross

  dim3 tb32(32, 8);
  cast2_f32_bf16<<<8192, 256, 0, stream>>>(hidden, enc, hid_b, enc_b, 1048576);
  transpose_cast_qkv<<<dim3(8, 64, 32), tb32, 0, stream>>>(q_w, k_w, v_w, wqkvt);
  transpose_cast<<<dim3(64, 128, 1), tb32, 0, stream>>>(o_w, owt, 4096, 2048);
  gemm_proj<<<dim3(96, 16), 256, 0, stream>>>(hid_b, enc_b, wqkvt, cself, ccross);
  norm_finalize<true><<<8192, 256, 0, stream>>>(cself, 8192, 0, q_s, pos, qb, 16, 1024, 0, 0.0625f);
  norm_finalize<true><<<4096, 256, 0, stream>>>(cself, 8192, 4096, k_s, pos, kbuf, 8, 2048, 0, 1.0f);
  norm_finalize<false><<<4096, 256, 0, stream>>>(ccross, 4096, 0, k_s, nullptr, kbuf, 8, 2048, 1024, 1.0f);
  transpose_v2<<<dim3(8, 32, 32), tb32, 0, stream>>>(cself + 6144, ccross + 2048, vtb);
  attn_kernel<<<dim3(32, 16), 512, 0, stream>>>(qb, kbuf, vtb, attn_b);
  gemm_osplit<<<dim3(16, 16, 2), 256, 0, stream>>>(attn_b, owt, out, p1);
  add_inplace<<<4096, 256, 0, stream>>>(out, p1, 1048576);
}